// Round 4
// baseline (20.907 us; speedup 1.0000x reference)
//
#include <hip/hip_runtime.h>

#define BT 32            // output tile (32x32 per 256-thread block)
#define HT 34            // halo rows/cols = BT+2
#define RW 40            // raw LDS cols: [w0-4, w0+36), float4-aligned
#define KP 35            // k-plane pitch
#define NQ 10            // float4 quads per halo row
#define NITEM (HT * NQ)  // 340 quad-items per block

__global__ __launch_bounds__(256) void smap_fused(
    const float* __restrict__ x, const float* __restrict__ cam,
    float* __restrict__ out, int B, int H, int W)
{
    __shared__ float sxr[HT][RW];
    __shared__ float syr[HT][RW];
    __shared__ float szr[HT][RW];
    __shared__ float srr[HT][RW];
    __shared__ float skf[HT][KP];    // k code as int-bits

    const int b  = blockIdx.z;
    const int h0 = blockIdx.y * BT;
    const int w0 = blockIdx.x * BT;
    const int tx = threadIdx.x;          // 0..31
    const int ty = threadIdx.y;          // 0..7
    const int tid = ty * 32 + tx;

    // ---- 3x3 inverse of cam (adjugate / det): bitwise-matches LAPACK's
    // triangular-solve inversion for this cam (verified absmax 0.0) ----
    const float a00 = cam[0], a01 = cam[1], a02 = cam[2];
    const float a10 = cam[3], a11 = cam[4], a12 = cam[5];
    const float a20 = cam[6], a21 = cam[7], a22 = cam[8];
    const float m00 = a11 * a22 - a12 * a21;
    const float m01 = a10 * a22 - a12 * a20;
    const float m02 = a10 * a21 - a11 * a20;
    const float det = a00 * m00 - a01 * m01 + a02 * m02;
    const float i00 = m00 / det;
    const float i01 = (a02 * a21 - a01 * a22) / det;
    const float i02 = (a01 * a12 - a02 * a11) / det;
    const float i10 = (a12 * a20 - a10 * a22) / det;
    const float i11 = (a00 * a22 - a02 * a20) / det;
    const float i12 = (a02 * a10 - a00 * a12) / det;
    const float i20 = m02 / det;
    const float i21 = (a01 * a20 - a00 * a21) / det;
    const float i22 = (a00 * a11 - a01 * a10) / det;

    // r2 == 1.0f exactly when i20==+-0, i21==+-0, i22==1 -> skip divides.
    const bool fastcam = (i20 == 0.0f) && (i21 == 0.0f) && (i22 == 1.0f);
    // Separable costs (bit-exact) when additionally i01==+0 and i10==+0:
    // fadd(A,+0)==A except A==-0, and squaring erases the sign of zero.
    const bool fastsep = fastcam &&
        (__float_as_uint(i01) == 0u) && (__float_as_uint(i10) == 0u);

    const size_t HW = (size_t)H * W;
    const float* xb = x + (size_t)b * 4 * HW;

    // ---- quad loader: 4 channels x float4 at (halo row, quad q) ----
    auto ldq = [&](int row, int q, float4& X, float4& Y, float4& Z, float4& R) {
        X = make_float4(0.f, 0.f, 0.f, 0.f); Y = X; Z = X; R = X;
        const int gh = h0 - 1 + row;
        const int gc = w0 - 4 + 4 * q;
        if (gh >= 0 && gh < H) {
            if (gc >= 0 && gc + 4 <= W) {
                const size_t base = (size_t)gh * W + gc;
                X = *(const float4*)(xb + base);
                Y = *(const float4*)(xb + HW + base);
                Z = *(const float4*)(xb + 2 * HW + base);
                R = *(const float4*)(xb + 3 * HW + base);
            } else {
                float* Xa = (float*)&X; float* Ya = (float*)&Y;
                float* Za = (float*)&Z; float* Ra = (float*)&R;
                #pragma unroll
                for (int e = 0; e < 4; ++e) {
                    const int c = gc + e;
                    if (c >= 0 && c < W) {
                        const size_t off = (size_t)gh * W + c;
                        Xa[e] = xb[off];
                        Ya[e] = xb[HW + off];
                        Za[e] = xb[2 * HW + off];
                        Ra[e] = xb[3 * HW + off];
                    }
                }
            }
        }
    };

    // ---- per-pixel k code (identical rounded-op sequence to verified kernel)
    auto kcode = [&](float xv, float yv, float zv, float rm, int gh, int gw) -> int {
        const float zs = (zv > 0.f) ? zv : 1.0f;
        const float px = __fdiv_rn(xv, zs);
        const float py = __fdiv_rn(yv, zs);
        float best = __builtin_inff();
        int bi = 0;
        if (fastsep) {
            float f[3], g[3];
            #pragma unroll
            for (int t = 0; t < 3; ++t) {
                const float u  = (float)(gw + t);
                const float rx = __fadd_rn(__fmul_rn(i00, u), i02);
                const float dx = __fsub_rn(px, rx);
                f[t] = __fmul_rn(dx, dx);
            }
            #pragma unroll
            for (int s = 0; s < 3; ++s) {
                const float v  = (float)(gh + s);
                const float ry = __fadd_rn(__fmul_rn(i11, v), i12);
                const float dy = __fsub_rn(py, ry);
                g[s] = __fmul_rn(dy, dy);
            }
            #pragma unroll
            for (int n = 0; n < 9; ++n) {   // n order: tie semantics == jnp.argmin
                const float c = __fadd_rn(f[n % 3], g[n / 3]);
                if (c < best) { best = c; bi = n; }
            }
        } else {
            float A0[3], A1[3], B0[3], B1[3];
            #pragma unroll
            for (int t = 0; t < 3; ++t) {
                const float u = (float)(gw + t);
                A0[t] = __fmul_rn(i00, u);
                A1[t] = __fmul_rn(i10, u);
            }
            #pragma unroll
            for (int s = 0; s < 3; ++s) {
                const float v = (float)(gh + s);
                B0[s] = __fmul_rn(i01, v);
                B1[s] = __fmul_rn(i11, v);
            }
            #pragma unroll
            for (int n = 0; n < 9; ++n) {
                const int s = n / 3, t = n % 3;
                const float r0 = __fadd_rn(__fadd_rn(A0[t], B0[s]), i02);
                const float r1 = __fadd_rn(__fadd_rn(A1[t], B1[s]), i12);
                float rx, ry;
                if (fastcam) { rx = r0; ry = r1; }
                else {
                    const float u = (float)(gw + t), v = (float)(gh + s);
                    const float r2 = __fadd_rn(__fadd_rn(__fmul_rn(i20, u), __fmul_rn(i21, v)), i22);
                    rx = __fdiv_rn(r0, r2);
                    ry = __fdiv_rn(r1, r2);
                }
                const float dx = __fsub_rn(px, rx);
                const float dy = __fsub_rn(py, ry);
                const float c  = __fadd_rn(__fmul_rn(dx, dx), __fmul_rn(dy, dy));
                if (c < best) { best = c; bi = n; }
            }
        }
        const bool validp = (rm > 0.5f) && (zv > 0.0f);
        const bool badp   = (rm > 0.5f) && !(zv > 0.0f);
        return validp ? bi : (badp ? 4 : 9);
    };

    // ---- quad processor: stage raw planes + compute k for its 4 pixels ----
    auto proc = [&](int row, int q, const float4& X, const float4& Y,
                    const float4& Z, const float4& R) {
        *(float4*)&sxr[row][4 * q] = X;
        *(float4*)&syr[row][4 * q] = Y;
        *(float4*)&szr[row][4 * q] = Z;
        *(float4*)&srr[row][4 * q] = R;
        const int gh = h0 - 1 + row;
        const float Xa[4] = {X.x, X.y, X.z, X.w};
        const float Ya[4] = {Y.x, Y.y, Y.z, Y.w};
        const float Za[4] = {Z.x, Z.y, Z.z, Z.w};
        const float Ra[4] = {R.x, R.y, R.z, R.w};
        #pragma unroll
        for (int e = 0; e < 4; ++e) {
            const int j = 4 * q + e - 3;            // halo pixel col
            if (j < 0 || j >= HT) continue;
            const int gw = w0 - 1 + j;
            skf[row][j] = __int_as_float(kcode(Xa[e], Ya[e], Za[e], Ra[e], gh, gw));
        }
    };

    // ---- Pass 1: issue ALL global loads up-front (max MLP), then process ----
    {
        const int item0 = tid;              // always < NITEM (256 < 340)
        const int item1 = tid + 256;
        const bool act1 = item1 < NITEM;
        const int row0 = item0 / NQ, q0 = item0 - row0 * NQ;
        const int row1 = item1 / NQ, q1 = item1 - row1 * NQ;
        float4 X0, Y0, Z0, R0, X1, Y1, Z1, R1;
        ldq(row0, q0, X0, Y0, Z0, R0);
        if (act1) ldq(row1, q1, X1, Y1, Z1, R1);
        proc(row0, q0, X0, Y0, Z0, R0);
        if (act1) proc(row1, q1, X1, Y1, Z1, R1);
    }
    __syncthreads();

    // ---- Pass 2: thread owns col tx, output rows 4*ty..4*ty+3; rolling
    // 3-row register window; first-min over the 9 scattered-in z ----
    const int rbase = 4 * ty;
    float zA[3], zB[3], zC[3];
    int   kA[3], kB[3], kC[3];
    #pragma unroll
    for (int c = 0; c < 3; ++c) {
        zA[c] = szr[rbase][tx + 3 + c];
        kA[c] = __float_as_int(skf[rbase][tx + c]);
        zB[c] = szr[rbase + 1][tx + 3 + c];
        kB[c] = __float_as_int(skf[rbase + 1][tx + c]);
    }

    #pragma unroll
    for (int q = 0; q < 4; ++q) {
        const int rq = rbase + q;            // output row (tile coords); center = halo row rq+1
        #pragma unroll
        for (int c = 0; c < 3; ++c) {
            zC[c] = szr[rq + 2][tx + 3 + c];
            kC[c] = __float_as_int(skf[rq + 2][tx + c]);
        }

        float bz = 1e10f;
        int bli = rq + 1, blj = tx + 1;      // fallback: center
        #pragma unroll
        for (int t = 0; t < 3; ++t) {        // n = 0..2 -> halo row rq+2, col tx+2-t
            const float z = zC[2 - t];
            const float cand = (kC[2 - t] == t && z > 0.f) ? z : 1e10f;
            if (cand < bz) { bz = cand; bli = rq + 2; blj = tx + 2 - t; }
        }
        #pragma unroll
        for (int t = 0; t < 3; ++t) {        // n = 3..5 -> halo row rq+1
            const float z = zB[2 - t];
            const float cand = (kB[2 - t] == 3 + t && z > 0.f) ? z : 1e10f;
            if (cand < bz) { bz = cand; bli = rq + 1; blj = tx + 2 - t; }
        }
        #pragma unroll
        for (int t = 0; t < 3; ++t) {        // n = 6..8 -> halo row rq
            const float z = zA[2 - t];
            const float cand = (kA[2 - t] == 6 + t && z > 0.f) ? z : 1e10f;
            if (cand < bz) { bz = cand; bli = rq; blj = tx + 2 - t; }
        }
        const bool found = bz < 1e10f;

        const float vx  = sxr[bli][blj + 3];
        const float vy  = syr[bli][blj + 3];
        const float vrm = srr[bli][blj + 3];

        float ox, oy, oz, orm;
        if (found) {
            ox = vx; oy = vy; oz = bz; orm = vrm;
        } else {
            const int   kc = kB[1];                    // center code
            const float zc = zB[1];                    // center z
            const bool  k4 = (kc == 4);                // w_det(1,1) == 1
            const bool  validp = (vrm > 0.5f) && (zc > 0.f);
            ox = k4 ? vx : 0.f;
            oy = k4 ? vy : 0.f;
            oz = k4 ? zc : 0.f;
            orm = (k4 || !validp) ? vrm : 0.f;         // w2(1,1)
        }

        const int h = h0 + rq, w = w0 + tx;
        const size_t obase = (size_t)b * 4 * HW + (size_t)h * W + w;
        __builtin_nontemporal_store(ox,  &out[obase]);
        __builtin_nontemporal_store(oy,  &out[obase + HW]);
        __builtin_nontemporal_store(oz,  &out[obase + 2 * HW]);
        __builtin_nontemporal_store(orm, &out[obase + 3 * HW]);

        #pragma unroll
        for (int c = 0; c < 3; ++c) {
            zA[c] = zB[c]; kA[c] = kB[c];
            zB[c] = zC[c]; kB[c] = kC[c];
        }
    }
}

extern "C" void kernel_launch(void* const* d_in, const int* in_sizes, int n_in,
                              void* d_out, int out_size, void* d_ws, size_t ws_size,
                              hipStream_t stream) {
    const float* x   = (const float*)d_in[0];
    const float* cam = (const float*)d_in[1];
    float* out = (float*)d_out;
    const int H = 512, W = 640;
    const int B = in_sizes[0] / (4 * H * W);
    dim3 block(32, 8);
    dim3 grid((W + BT - 1) / BT, (H + BT - 1) / BT, B);  // 20 x 16 x B
    hipLaunchKernelGGL(smap_fused, grid, block, 0, stream, x, cam, out, B, H, W);
}

// Round 5
// 20.440 us; speedup vs baseline: 1.0229x; 1.0229x over previous
//
#include <hip/hip_runtime.h>

#define BT 16            // output tile (16x16, one pixel per thread in pass 2)
#define HT 18            // halo = BT+2
#define PP 19            // zk-plane pitch (float2)

// Generic-cam path (never taken for the benchmark cam): noinline keeps its
// divide-heavy code out of the hot path's register budget. Bit-identical
// rounded-op sequence to the verified (absmax 0.0) round-2/3 kernels.
__device__ __attribute__((noinline))
int kcode_generic(float px, float py, int gh, int gw,
                  float i00, float i01, float i02,
                  float i10, float i11, float i12,
                  float i20, float i21, float i22, int fastcam)
{
    float A0[3], A1[3], B0[3], B1[3];
    #pragma unroll
    for (int t = 0; t < 3; ++t) {
        const float u = (float)(gw + t);
        A0[t] = __fmul_rn(i00, u);
        A1[t] = __fmul_rn(i10, u);
    }
    #pragma unroll
    for (int s = 0; s < 3; ++s) {
        const float v = (float)(gh + s);
        B0[s] = __fmul_rn(i01, v);
        B1[s] = __fmul_rn(i11, v);
    }
    float best = __builtin_inff();
    int bi = 0;
    #pragma unroll
    for (int n = 0; n < 9; ++n) {
        const int s = n / 3, t = n % 3;
        const float r0 = __fadd_rn(__fadd_rn(A0[t], B0[s]), i02);
        const float r1 = __fadd_rn(__fadd_rn(A1[t], B1[s]), i12);
        float rx, ry;
        if (fastcam) { rx = r0; ry = r1; }
        else {
            const float u = (float)(gw + t), v = (float)(gh + s);
            const float r2 = __fadd_rn(__fadd_rn(__fmul_rn(i20, u), __fmul_rn(i21, v)), i22);
            rx = __fdiv_rn(r0, r2);
            ry = __fdiv_rn(r1, r2);
        }
        const float dx = __fsub_rn(px, rx);
        const float dy = __fsub_rn(py, ry);
        const float c  = __fadd_rn(__fmul_rn(dx, dx), __fmul_rn(dy, dy));
        if (c < best) { best = c; bi = n; }
    }
    return bi;
}

__global__ __launch_bounds__(256, 8) void smap_fused(
    const float* __restrict__ x, const float* __restrict__ cam,
    float* __restrict__ out, int B, int H, int W)
{
    __shared__ float2 szk[HT][PP];       // (z, k-as-bits) only: 2.7 KB/block

    // ---- tile id with XCD-contiguous swizzle (bijective: ntiles % 8 == 0) --
    const int tiles_x = W / BT, tiles_y = H / BT;      // 40, 32 (exact)
    const int ntiles = tiles_x * tiles_y * B;          // 5120
    int bid = blockIdx.x + tiles_x * (blockIdx.y + tiles_y * blockIdx.z);
    if ((ntiles & 7) == 0) bid = (bid & 7) * (ntiles >> 3) + (bid >> 3);
    const int txt = bid % tiles_x;
    const int rest = bid / tiles_x;
    const int tyt = rest % tiles_y;
    const int b   = rest / tiles_y;

    const int h0 = tyt * BT, w0 = txt * BT;
    const int tx = threadIdx.x;          // 0..15
    const int ty = threadIdx.y;          // 0..15
    const int tid = ty * 16 + tx;

    // ---- 3x3 inverse of cam (adjugate / det): bitwise-matches LAPACK's
    // triangular-solve inversion for this cam (verified absmax 0.0) ----
    const float a00 = cam[0], a01 = cam[1], a02 = cam[2];
    const float a10 = cam[3], a11 = cam[4], a12 = cam[5];
    const float a20 = cam[6], a21 = cam[7], a22 = cam[8];
    const float m00 = a11 * a22 - a12 * a21;
    const float m01 = a10 * a22 - a12 * a20;
    const float m02 = a10 * a21 - a11 * a20;
    const float det = a00 * m00 - a01 * m01 + a02 * m02;
    const float i00 = m00 / det;
    const float i01 = (a02 * a21 - a01 * a22) / det;
    const float i02 = (a01 * a12 - a02 * a11) / det;
    const float i10 = (a12 * a20 - a10 * a22) / det;
    const float i11 = (a00 * a22 - a02 * a20) / det;
    const float i12 = (a02 * a10 - a00 * a12) / det;
    const float i20 = m02 / det;
    const float i21 = (a01 * a20 - a00 * a21) / det;
    const float i22 = (a00 * a11 - a01 * a10) / det;

    // r2 == 1.0f exactly when i20==+-0, i21==+-0, i22==1 -> divides vanish.
    const bool fastcam = (i20 == 0.0f) && (i21 == 0.0f) && (i22 == 1.0f);
    // Separable costs (bit-exact) when additionally i01==+0 and i10==+0:
    // fadd(A,+0)==A except A==-0, and squaring erases the sign of zero.
    const bool fastsep = fastcam &&
        (__float_as_uint(i01) == 0u) && (__float_as_uint(i10) == 0u);

    const size_t HW = (size_t)H * W;
    const float* xb = x + (size_t)b * 4 * HW;

    // ---- Pass 1: halo tile -> (z, code k); k in 0..8, 4=bad, 9=none ----
    for (int item = tid; item < HT * HT; item += 256) {
        const int i = item / HT, j = item - i * HT;
        const int gh = h0 - 1 + i, gw = w0 - 1 + j;
        float xv = 0.f, yv = 0.f, zv = 0.f, rm = 0.f;
        if (gh >= 0 && gh < H && gw >= 0 && gw < W) {
            const size_t off = (size_t)gh * W + gw;
            xv = xb[off];
            yv = xb[HW + off];
            zv = xb[2 * HW + off];
            rm = xb[3 * HW + off];
        }
        // reference: zs = where(z>0, z, 1); px = x/zs
        const float zs = (zv > 0.f) ? zv : 1.0f;
        const float px = __fdiv_rn(xv, zs);
        const float py = __fdiv_rn(yv, zs);

        int bi;
        if (fastsep) {
            float f[3], g[3];
            #pragma unroll
            for (int t = 0; t < 3; ++t) {
                const float u  = (float)(gw + t);
                const float rx = __fadd_rn(__fmul_rn(i00, u), i02);
                const float dx = __fsub_rn(px, rx);
                f[t] = __fmul_rn(dx, dx);
            }
            #pragma unroll
            for (int s = 0; s < 3; ++s) {
                const float v  = (float)(gh + s);
                const float ry = __fadd_rn(__fmul_rn(i11, v), i12);
                const float dy = __fsub_rn(py, ry);
                g[s] = __fmul_rn(dy, dy);
            }
            float best = __builtin_inff();
            bi = 0;
            #pragma unroll
            for (int n = 0; n < 9; ++n) {  // n order: tie semantics == jnp.argmin
                const float c = __fadd_rn(f[n % 3], g[n / 3]);
                if (c < best) { best = c; bi = n; }
            }
        } else {
            bi = kcode_generic(px, py, gh, gw, i00, i01, i02,
                               i10, i11, i12, i20, i21, i22, (int)fastcam);
        }

        const bool validp = (rm > 0.5f) && (zv > 0.0f);
        const bool badp   = (rm > 0.5f) && !(zv > 0.0f);
        const int k = validp ? bi : (badp ? 4 : 9);
        szk[i][j] = make_float2(zv, __int_as_float(k));
    }
    __syncthreads();

    // ---- Pass 2: one output pixel per thread; first-min over the 9
    // scattered-in z; winner's (x,y,rm) re-read from global (L1/L2-hot) ----
    float2 cA[3], cB[3], cC[3];
    #pragma unroll
    for (int c = 0; c < 3; ++c) {
        cA[c] = szk[ty][tx + c];         // halo row ty     (n = 6..8)
        cB[c] = szk[ty + 1][tx + c];     // halo row ty+1   (n = 3..5)
        cC[c] = szk[ty + 2][tx + c];     // halo row ty+2   (n = 0..2)
    }

    float bz = 1e10f;
    int bli = ty + 1, blj = tx + 1;      // fallback: center
    #pragma unroll
    for (int t = 0; t < 3; ++t) {        // n = 0..2 -> halo row ty+2, col tx+2-t
        const float z = cC[2 - t].x;
        const int   k = __float_as_int(cC[2 - t].y);
        const float cand = (k == t && z > 0.f) ? z : 1e10f;
        if (cand < bz) { bz = cand; bli = ty + 2; blj = tx + 2 - t; }
    }
    #pragma unroll
    for (int t = 0; t < 3; ++t) {        // n = 3..5 -> halo row ty+1
        const float z = cB[2 - t].x;
        const int   k = __float_as_int(cB[2 - t].y);
        const float cand = (k == 3 + t && z > 0.f) ? z : 1e10f;
        if (cand < bz) { bz = cand; bli = ty + 1; blj = tx + 2 - t; }
    }
    #pragma unroll
    for (int t = 0; t < 3; ++t) {        // n = 6..8 -> halo row ty
        const float z = cA[2 - t].x;
        const int   k = __float_as_int(cA[2 - t].y);
        const float cand = (k == 6 + t && z > 0.f) ? z : 1e10f;
        if (cand < bz) { bz = cand; bli = ty; blj = tx + 2 - t; }
    }
    const bool found = bz < 1e10f;

    // winner (or center) global coords are always in-image
    const size_t woff = (size_t)(h0 - 1 + bli) * W + (w0 - 1 + blj);
    const float vx  = xb[woff];
    const float vy  = xb[HW + woff];
    const float vrm = xb[3 * HW + woff];

    float ox, oy, oz, orm;
    if (found) {
        ox = vx; oy = vy; oz = bz; orm = vrm;
    } else {
        const int   kc = __float_as_int(cB[1].y);  // center code
        const float zc = cB[1].x;                  // center z
        const bool  k4 = (kc == 4);                // w_det(1,1) == 1
        const bool  validp = (vrm > 0.5f) && (zc > 0.f);
        ox = k4 ? vx : 0.f;
        oy = k4 ? vy : 0.f;
        oz = k4 ? zc : 0.f;
        orm = (k4 || !validp) ? vrm : 0.f;         // w2(1,1)
    }

    const int h = h0 + ty, w = w0 + tx;
    const size_t obase = (size_t)b * 4 * HW + (size_t)h * W + w;
    __builtin_nontemporal_store(ox,  &out[obase]);
    __builtin_nontemporal_store(oy,  &out[obase + HW]);
    __builtin_nontemporal_store(oz,  &out[obase + 2 * HW]);
    __builtin_nontemporal_store(orm, &out[obase + 3 * HW]);
}

extern "C" void kernel_launch(void* const* d_in, const int* in_sizes, int n_in,
                              void* d_out, int out_size, void* d_ws, size_t ws_size,
                              hipStream_t stream) {
    const float* x   = (const float*)d_in[0];
    const float* cam = (const float*)d_in[1];
    float* out = (float*)d_out;
    const int H = 512, W = 640;
    const int B = in_sizes[0] / (4 * H * W);
    dim3 block(16, 16);
    dim3 grid(W / BT, H / BT, B);        // 40 x 32 x B = 5120 blocks
    hipLaunchKernelGGL(smap_fused, grid, block, 0, stream, x, cam, out, B, H, W);
}

// Round 6
// 16.348 us; speedup vs baseline: 1.2789x; 1.2503x over previous
//
#include <hip/hip_runtime.h>

#define BT 32            // output tile (32x32 per 256-thread block)
#define HT (BT + 2)      // halo tile = 34
#define PP (HT + 1)      // LDS row pitch = 35

// Generic-cam path (never taken for the benchmark cam): noinline keeps its
// divide-heavy code out of the hot path's register budget. Bit-identical
// rounded-op sequence to the verified (absmax 0.0) round-2/3 kernels.
__device__ __attribute__((noinline))
int kcode_generic(float px, float py, int gh, int gw,
                  float i00, float i01, float i02,
                  float i10, float i11, float i12,
                  float i20, float i21, float i22, int fastcam)
{
    float A0[3], A1[3], B0[3], B1[3];
    #pragma unroll
    for (int t = 0; t < 3; ++t) {
        const float u = (float)(gw + t);
        A0[t] = __fmul_rn(i00, u);
        A1[t] = __fmul_rn(i10, u);
    }
    #pragma unroll
    for (int s = 0; s < 3; ++s) {
        const float v = (float)(gh + s);
        B0[s] = __fmul_rn(i01, v);
        B1[s] = __fmul_rn(i11, v);
    }
    float best = __builtin_inff();
    int bi = 0;
    #pragma unroll
    for (int n = 0; n < 9; ++n) {
        const int s = n / 3, t = n % 3;
        const float r0 = __fadd_rn(__fadd_rn(A0[t], B0[s]), i02);
        const float r1 = __fadd_rn(__fadd_rn(A1[t], B1[s]), i12);
        float rx, ry;
        if (fastcam) { rx = r0; ry = r1; }
        else {
            const float u = (float)(gw + t), v = (float)(gh + s);
            const float r2 = __fadd_rn(__fadd_rn(__fmul_rn(i20, u), __fmul_rn(i21, v)), i22);
            rx = __fdiv_rn(r0, r2);
            ry = __fdiv_rn(r1, r2);
        }
        const float dx = __fsub_rn(px, rx);
        const float dy = __fsub_rn(py, ry);
        const float c  = __fadd_rn(__fmul_rn(dx, dx), __fmul_rn(dy, dy));
        if (c < best) { best = c; bi = n; }
    }
    return bi;
}

__global__ __launch_bounds__(256, 8) void smap_fused(
    const float* __restrict__ x, const float* __restrict__ cam,
    float* __restrict__ out, int B, int H, int W)
{
    __shared__ float2 szk[HT][PP];       // (z, k-as-bits) only: 9.5 KB/block

    // ---- tile id with XCD-contiguous swizzle (bijective: ntiles % 8 == 0) --
    const int tiles_x = W / BT, tiles_y = H / BT;      // 20, 16 (exact)
    const int ntiles = tiles_x * tiles_y * B;          // 1280
    int bid = blockIdx.x + tiles_x * (blockIdx.y + tiles_y * blockIdx.z);
    if ((ntiles & 7) == 0) bid = (bid & 7) * (ntiles >> 3) + (bid >> 3);
    const int txt = bid % tiles_x;
    const int rest = bid / tiles_x;
    const int tyt = rest % tiles_y;
    const int b   = rest / tiles_y;

    const int h0 = tyt * BT, w0 = txt * BT;
    const int tx = threadIdx.x;          // 0..31
    const int ty = threadIdx.y;          // 0..7
    const int tid = ty * 32 + tx;

    // ---- 3x3 inverse of cam (adjugate / det): bitwise-matches LAPACK's
    // triangular-solve inversion for this cam (verified absmax 0.0) ----
    const float a00 = cam[0], a01 = cam[1], a02 = cam[2];
    const float a10 = cam[3], a11 = cam[4], a12 = cam[5];
    const float a20 = cam[6], a21 = cam[7], a22 = cam[8];
    const float m00 = a11 * a22 - a12 * a21;
    const float m01 = a10 * a22 - a12 * a20;
    const float m02 = a10 * a21 - a11 * a20;
    const float det = a00 * m00 - a01 * m01 + a02 * m02;
    const float i00 = m00 / det;
    const float i01 = (a02 * a21 - a01 * a22) / det;
    const float i02 = (a01 * a12 - a02 * a11) / det;
    const float i10 = (a12 * a20 - a10 * a22) / det;
    const float i11 = (a00 * a22 - a02 * a20) / det;
    const float i12 = (a02 * a10 - a00 * a12) / det;
    const float i20 = m02 / det;
    const float i21 = (a01 * a20 - a00 * a21) / det;
    const float i22 = (a00 * a11 - a01 * a10) / det;

    // r2 == 1.0f exactly when i20==+-0, i21==+-0, i22==1 -> divides vanish.
    const bool fastcam = (i20 == 0.0f) && (i21 == 0.0f) && (i22 == 1.0f);
    // Separable costs (bit-exact) when additionally i01==+0 and i10==+0:
    // fadd(A,+0)==A except A==-0, and squaring erases the sign of zero.
    const bool fastsep = fastcam &&
        (__float_as_uint(i01) == 0u) && (__float_as_uint(i10) == 0u);

    const size_t HW = (size_t)H * W;
    const float* xb = x + (size_t)b * 4 * HW;

    // ---- Pass 1: halo tile -> (z, code k); k in 0..8, 4=bad, 9=none ----
    for (int item = tid; item < HT * HT; item += 256) {
        const int i = item / HT, j = item - i * HT;
        const int gh = h0 - 1 + i, gw = w0 - 1 + j;
        float xv = 0.f, yv = 0.f, zv = 0.f, rm = 0.f;
        if (gh >= 0 && gh < H && gw >= 0 && gw < W) {
            const size_t off = (size_t)gh * W + gw;
            xv = xb[off];
            yv = xb[HW + off];
            zv = xb[2 * HW + off];
            rm = xb[3 * HW + off];
        }
        // reference: zs = where(z>0, z, 1); px = x/zs
        const float zs = (zv > 0.f) ? zv : 1.0f;
        const float px = __fdiv_rn(xv, zs);
        const float py = __fdiv_rn(yv, zs);

        int bi;
        if (fastsep) {
            float f[3], g[3];
            #pragma unroll
            for (int t = 0; t < 3; ++t) {
                const float u  = (float)(gw + t);
                const float rx = __fadd_rn(__fmul_rn(i00, u), i02);
                const float dx = __fsub_rn(px, rx);
                f[t] = __fmul_rn(dx, dx);
            }
            #pragma unroll
            for (int s = 0; s < 3; ++s) {
                const float v  = (float)(gh + s);
                const float ry = __fadd_rn(__fmul_rn(i11, v), i12);
                const float dy = __fsub_rn(py, ry);
                g[s] = __fmul_rn(dy, dy);
            }
            float best = __builtin_inff();
            bi = 0;
            #pragma unroll
            for (int n = 0; n < 9; ++n) {  // n order: tie semantics == jnp.argmin
                const float c = __fadd_rn(f[n % 3], g[n / 3]);
                if (c < best) { best = c; bi = n; }
            }
        } else {
            bi = kcode_generic(px, py, gh, gw, i00, i01, i02,
                               i10, i11, i12, i20, i21, i22, (int)fastcam);
        }

        const bool validp = (rm > 0.5f) && (zv > 0.0f);
        const bool badp   = (rm > 0.5f) && !(zv > 0.0f);
        const int k = validp ? bi : (badp ? 4 : 9);
        szk[i][j] = make_float2(zv, __int_as_float(k));
    }
    __syncthreads();

    // ---- Pass 2: thread owns col tx, output rows 4*ty..4*ty+3; rolling
    // 3-row register window; first-min over the 9 scattered-in z ----
    const int rbase = 4 * ty;
    float2 rA[3], rB[3], rC[3];
    #pragma unroll
    for (int c = 0; c < 3; ++c) {
        rA[c] = szk[rbase][tx + c];          // halo row rbase
        rB[c] = szk[rbase + 1][tx + c];      // halo row rbase+1
    }

    #pragma unroll
    for (int q = 0; q < 4; ++q) {
        const int rq = rbase + q;            // output row; center = halo row rq+1
        #pragma unroll
        for (int c = 0; c < 3; ++c) rC[c] = szk[rq + 2][tx + c];

        float bz = 1e10f;
        int bli = rq + 1, blj = tx + 1;      // fallback: center
        #pragma unroll
        for (int t = 0; t < 3; ++t) {        // n = 0..2 -> halo row rq+2, col tx+2-t
            const float z = rC[2 - t].x;
            const int   k = __float_as_int(rC[2 - t].y);
            const float cand = (k == t && z > 0.f) ? z : 1e10f;
            if (cand < bz) { bz = cand; bli = rq + 2; blj = tx + 2 - t; }
        }
        #pragma unroll
        for (int t = 0; t < 3; ++t) {        // n = 3..5 -> halo row rq+1
            const float z = rB[2 - t].x;
            const int   k = __float_as_int(rB[2 - t].y);
            const float cand = (k == 3 + t && z > 0.f) ? z : 1e10f;
            if (cand < bz) { bz = cand; bli = rq + 1; blj = tx + 2 - t; }
        }
        #pragma unroll
        for (int t = 0; t < 3; ++t) {        // n = 6..8 -> halo row rq
            const float z = rA[2 - t].x;
            const int   k = __float_as_int(rA[2 - t].y);
            const float cand = (k == 6 + t && z > 0.f) ? z : 1e10f;
            if (cand < bz) { bz = cand; bli = rq; blj = tx + 2 - t; }
        }
        const bool found = bz < 1e10f;

        // winner (or center) global coords are always in-image; these lines
        // were fetched by this block (or its XCD-neighbor) in pass 1 -> L1/L2 hot
        const size_t woff = (size_t)(h0 - 1 + bli) * W + (w0 - 1 + blj);
        const float vx  = xb[woff];
        const float vy  = xb[HW + woff];
        const float vrm = xb[3 * HW + woff];

        float ox, oy, oz, orm;
        if (found) {
            ox = vx; oy = vy; oz = bz; orm = vrm;
        } else {
            const int   kc = __float_as_int(rB[1].y);  // center code
            const float zc = rB[1].x;                  // center z
            const bool  k4 = (kc == 4);                // w_det(1,1) == 1
            const bool  validp = (vrm > 0.5f) && (zc > 0.f);
            ox = k4 ? vx : 0.f;
            oy = k4 ? vy : 0.f;
            oz = k4 ? zc : 0.f;
            orm = (k4 || !validp) ? vrm : 0.f;         // w2(1,1)
        }

        const int h = h0 + rq, w = w0 + tx;
        const size_t obase = (size_t)b * 4 * HW + (size_t)h * W + w;
        __builtin_nontemporal_store(ox,  &out[obase]);
        __builtin_nontemporal_store(oy,  &out[obase + HW]);
        __builtin_nontemporal_store(oz,  &out[obase + 2 * HW]);
        __builtin_nontemporal_store(orm, &out[obase + 3 * HW]);

        #pragma unroll
        for (int c = 0; c < 3; ++c) { rA[c] = rB[c]; rB[c] = rC[c]; }
    }
}

extern "C" void kernel_launch(void* const* d_in, const int* in_sizes, int n_in,
                              void* d_out, int out_size, void* d_ws, size_t ws_size,
                              hipStream_t stream) {
    const float* x   = (const float*)d_in[0];
    const float* cam = (const float*)d_in[1];
    float* out = (float*)d_out;
    const int H = 512, W = 640;
    const int B = in_sizes[0] / (4 * H * W);
    dim3 block(32, 8);
    dim3 grid(W / BT, H / BT, B);        // 20 x 16 x B = 1280 blocks
    hipLaunchKernelGGL(smap_fused, grid, block, 0, stream, x, cam, out, B, H, W);
}